// Round 6
// baseline (76.167 us; speedup 1.0000x reference)
//
#include <hip/hip_runtime.h>
#include <math.h>

// DMLoss fused kernel for MI355X (gfx950).
// Round 6: R3 was LDS-ISSUE bound (96 broadcast ds_read_b128/thread; LDS pipe
// is per-CU). Fix by amortization: each thread owns P=4 points and scans an
// 8-segment slice (16-way split), so segment constants are read from LDS once
// per 4 point evaluations. LDS reads/thread: 96 -> ~30. VALU becomes binding
// (~6 us). Single kernel; final reduction fused via atomic ticket (verified).

#define BB 1024
#define NN 128
#define MM 128

__device__ __forceinline__ float sl1(float x) {
    float d = fabsf(x);
    return d < 1.0f ? 0.5f * d * d : d - 0.5f;
}

__global__ void __launch_bounds__(512, 8)
dmloss_main(const float* __restrict__ ini, const float* __restrict__ pred,
            const float* __restrict__ gt,  const float* __restrict__ kmask,
            float* __restrict__ pA, float* __restrict__ pB, float* __restrict__ pC,
            unsigned* __restrict__ counter, float* __restrict__ out)
{
    const int b   = blockIdx.x;
    const int tid = threadIdx.x;
    const int g   = tid & 31;    // point group: owns points 4g..4g+3
    const int h   = tid >> 5;    // 0..15: scan slice (8 segments / 8 ini points)

    __shared__ float2 s_gt[MM];      // raw gt points
    __shared__ float2 s_pr[NN];      // pred points (epilogue C gather)
    __shared__ float2 s_ii[NN];      // ini points (Phase C scan)
    __shared__ float4 s_segA[MM];    // (ax, ay, ex/10, ey/10), a = gt[m-1]
    __shared__ float2 s_segB[MM];    // (-ex*10/|e|^2, -ey*10/|e|^2)
    __shared__ float  s_step[16];    // exact j/10
    __shared__ float  s_rv[16 * 128];
    __shared__ float  s_rf[16 * 128];
    __shared__ float  s_sum[3][8];
    __shared__ int    s_last;

    const float2* gt2 = (const float2*)(gt   + (size_t)b * MM * 2);
    const float2* in2 = (const float2*)(ini  + (size_t)b * NN * 2);
    const float2* pr2 = (const float2*)(pred + (size_t)b * NN * 2);

    // ---- staging (one barrier) ----
    float2 myPr = make_float2(0.f, 0.f);
    float  myKm = 0.f;
    if (tid < 128) {
        int m = tid;
        float2 gm = gt2[m];
        float2 a  = gt2[(m + 127) & 127];
        s_gt[m] = gm;
        float ex = gm.x - a.x, ey = gm.y - a.y;
        float A  = ex * ex + ey * ey;
        float inv = A > 0.f ? 10.f / A : 0.f;   // degenerate seg -> vertex 0
        s_segA[m] = make_float4(a.x, a.y, ex * 0.1f, ey * 0.1f);
        s_segB[m] = make_float2(-ex * inv, -ey * inv);
        myPr = pr2[m];
        myKm = kmask[b * MM + m];
    } else if (tid < 256) {
        s_pr[tid - 128] = pr2[tid - 128];
    } else if (tid < 384) {
        s_ii[tid - 256] = in2[tid - 256];
    } else if (tid < 400) {
        s_step[tid - 384] = (float)(tid - 384) / 10.0f;
    }

    // Own pred points (= ini_pred) 4g..4g+3 : 8 consecutive floats, 32B aligned.
    float4 pv0 = *(const float4*)(&in2[4 * g]);
    float4 pv1 = *(const float4*)(&in2[4 * g + 2]);
    const float px0 = pv0.x, py0 = pv0.y, px1 = pv0.z, py1 = pv0.w;
    const float px2 = pv1.x, py2 = pv1.y, px3 = pv1.z, py3 = pv1.w;
    __syncthreads();

    float sumA = 0.f, sumB = 0.f, sumC = 0.f;

    // ---- Phase B: 4 owned pred points vs segment slice [8h, 8h+8) ----
    // Segment m: a=gt[m-1], e=gt[m]-a. q=a-p. jv=qx*Xn+qy*Yn (Xn=-ex*10/|e|^2).
    // Grid argmin at jr=rint(med3(jv,0,9)); d=|q+(e/10)*jr|^2. fi=10m+jr.
    float b0 = INFINITY, b1 = INFINITY, b2 = INFINITY, b3 = INFINITY;
    float f0 = 1e30f, f1 = 1e30f, f2 = 1e30f, f3 = 1e30f;
    {
        float fm = (float)(80 * h);     // 10 * (8h)
        const int m0 = 8 * h;
        #pragma unroll
        for (int j = 0; j < 8; ++j) {
            float4 SA = s_segA[m0 + j];               // 2-way broadcast b128
            float2 SB = s_segB[m0 + j];               // 2-way broadcast b64
            const float ax = SA.x, ay = SA.y, ux = SA.z, uy = SA.w;
            const float Xn = SB.x, Yn = SB.y;
            #define PAIR(px, py, bb, ff)                                   \
            {                                                              \
                float qx = ax - px, qy = ay - py;                          \
                float jv = fmaf(qy, Yn, qx * Xn);                          \
                float jr = rintf(__builtin_amdgcn_fmed3f(jv, 0.f, 9.f));   \
                float dx = fmaf(jr, ux, qx);                               \
                float dy = fmaf(jr, uy, qy);                               \
                float d  = fmaf(dy, dy, dx * dx);                          \
                float fi = fm + jr;                                        \
                if (d < bb) { bb = d; ff = fi; }                           \
            }
            PAIR(px0, py0, b0, f0)
            PAIR(px1, py1, b1, f1)
            PAIR(px2, py2, b2, f2)
            PAIR(px3, py3, b3, f3)
            #undef PAIR
            fm += 10.f;
        }
    }
    // packed result write: slots h*128 + 4g .. +3 (16B aligned)
    {
        float4* rv4 = (float4*)&s_rv[h * 128 + 4 * g];
        float4* rf4 = (float4*)&s_rf[h * 128 + 4 * g];
        *rv4 = make_float4(b0, b1, b2, b3);
        *rf4 = make_float4(f0, f1, f2, f3);
    }
    __syncthreads();

    // merge 16 slices per point + exact epilogue A
    if (tid < 128) {
        float best = s_rv[tid], bf = s_rf[tid];
        #pragma unroll
        for (int q = 1; q < 16; ++q) {
            float ov = s_rv[q * 128 + tid];
            float of = s_rf[q * 128 + tid];
            if (ov < best || (ov == best && of < bf)) { best = ov; bf = of; }
        }
        int bidx = (int)bf;
        int m = bidx / 10;
        int j = bidx - m * 10;
        float s  = s_step[j];
        float tt = 1.0f - s;
        float2 gm = s_gt[m];
        float2 gp = s_gt[(m + 127) & 127];
        float gx = gm.x * s + gp.x * tt;   // exact reference interp formula
        float gy = gm.y * s + gp.y * tt;
        sumA = sl1(myPr.x - gx) + sl1(myPr.y - gy);
    }
    __syncthreads();   // protect s_rv/s_rf reuse

    // ---- Phase C: 4 owned gt points vs ini slice [8h, 8h+8) ----
    {
        const float2* gt4 = &s_gt[4 * g];
        float2 ga = gt4[0], gb = gt4[1], gc = gt4[2], gd = gt4[3];
        b0 = INFINITY; b1 = INFINITY; b2 = INFINITY; b3 = INFINITY;
        f0 = 1e30f; f1 = 1e30f; f2 = 1e30f; f3 = 1e30f;
        float fk = (float)(8 * h);
        const int k0 = 8 * h;
        #pragma unroll
        for (int j = 0; j < 8; ++j) {
            float2 I = s_ii[k0 + j];                  // 2-way broadcast b64
            #define PAIRC(gp_, bb, ff)                                     \
            {                                                              \
                float dx = I.x - gp_.x, dy = I.y - gp_.y;                  \
                float d  = fmaf(dy, dy, dx * dx);                          \
                if (d < bb) { bb = d; ff = fk; }                           \
            }
            PAIRC(ga, b0, f0)
            PAIRC(gb, b1, f1)
            PAIRC(gc, b2, f2)
            PAIRC(gd, b3, f3)
            #undef PAIRC
            fk += 1.f;
        }
        float4* rv4 = (float4*)&s_rv[h * 128 + 4 * g];
        float4* rf4 = (float4*)&s_rf[h * 128 + 4 * g];
        *rv4 = make_float4(b0, b1, b2, b3);
        *rf4 = make_float4(f0, f1, f2, f3);
    }
    __syncthreads();

    if (tid < 128) {
        float best = s_rv[tid], bf = s_rf[tid];
        #pragma unroll
        for (int q = 1; q < 16; ++q) {
            float ov = s_rv[q * 128 + tid];
            float of = s_rf[q * 128 + tid];
            if (ov < best || (ov == best && of < bf)) { best = ov; bf = of; }
        }
        int k = (int)bf;
        float2 pk2 = s_pr[k];
        float2 g0  = s_gt[tid];
        sumB = myKm * (sl1(pk2.x - g0.x) + sl1(pk2.y - g0.y));
        sumC = myKm;
    }

    // ---- Block reduction of (sumA, sumB, sumC) ----
    #pragma unroll
    for (int off = 32; off > 0; off >>= 1) {
        sumA += __shfl_down(sumA, off);
        sumB += __shfl_down(sumB, off);
        sumC += __shfl_down(sumC, off);
    }
    const int wave = tid >> 6;
    if ((tid & 63) == 0) {
        s_sum[0][wave] = sumA; s_sum[1][wave] = sumB; s_sum[2][wave] = sumC;
    }
    __syncthreads();
    if (tid == 0) {
        float A = 0.f, Bs = 0.f, C = 0.f;
        #pragma unroll
        for (int w = 0; w < 8; ++w) {
            A += s_sum[0][w]; Bs += s_sum[1][w]; C += s_sum[2][w];
        }
        __hip_atomic_store(&pA[b], A,  __ATOMIC_RELAXED, __HIP_MEMORY_SCOPE_AGENT);
        __hip_atomic_store(&pB[b], Bs, __ATOMIC_RELAXED, __HIP_MEMORY_SCOPE_AGENT);
        __hip_atomic_store(&pC[b], C,  __ATOMIC_RELAXED, __HIP_MEMORY_SCOPE_AGENT);
        unsigned prev = __hip_atomic_fetch_add(counter, 1u, __ATOMIC_ACQ_REL,
                                               __HIP_MEMORY_SCOPE_AGENT);
        s_last = (prev == (unsigned)(BB - 1));
    }
    __syncthreads();

    // ---- Fused final reduction: exactly one block, fixed tid order ----
    if (s_last) {
        float A = 0.f, Bs = 0.f, C = 0.f;
        #pragma unroll
        for (int i = tid; i < BB; i += 512) {
            A  += __hip_atomic_load(&pA[i], __ATOMIC_RELAXED, __HIP_MEMORY_SCOPE_AGENT);
            Bs += __hip_atomic_load(&pB[i], __ATOMIC_RELAXED, __HIP_MEMORY_SCOPE_AGENT);
            C  += __hip_atomic_load(&pC[i], __ATOMIC_RELAXED, __HIP_MEMORY_SCOPE_AGENT);
        }
        #pragma unroll
        for (int off = 32; off > 0; off >>= 1) {
            A  += __shfl_down(A, off);
            Bs += __shfl_down(Bs, off);
            C  += __shfl_down(C, off);
        }
        if ((tid & 63) == 0) {
            s_sum[0][wave] = A; s_sum[1][wave] = Bs; s_sum[2][wave] = C;
        }
        __syncthreads();
        if (tid == 0) {
            float a = 0.f, bs = 0.f, c = 0.f;
            #pragma unroll
            for (int w = 0; w < 8; ++w) {
                a += s_sum[0][w]; bs += s_sum[1][w]; c += s_sum[2][w];
            }
            float loss_pred2gt = a / ((float)BB * (float)NN * 2.0f);
            float loss_set2set = bs / (2.0f * c + 1.0f) + loss_pred2gt;
            out[0] = 0.5f * loss_set2set;
        }
    }
}

extern "C" void kernel_launch(void* const* d_in, const int* in_sizes, int n_in,
                              void* d_out, int out_size, void* d_ws, size_t ws_size,
                              hipStream_t stream)
{
    const float* ini   = (const float*)d_in[0];
    const float* pred  = (const float*)d_in[1];
    const float* gt    = (const float*)d_in[2];
    const float* kmask = (const float*)d_in[3];

    float*    pA      = (float*)d_ws;             // [1024]
    float*    pB      = pA + BB;                  // [1024]
    float*    pC      = pB + BB;                  // [1024]
    unsigned* counter = (unsigned*)(pC + BB);     // [1]

    hipMemsetAsync(counter, 0, sizeof(unsigned), stream);
    dmloss_main<<<dim3(BB), dim3(512), 0, stream>>>(ini, pred, gt, kmask,
                                                    pA, pB, pC, counter,
                                                    (float*)d_out);
}

// Round 7
// 33.745 us; speedup vs baseline: 2.2571x; 2.2571x over previous
//
#include <hip/hip_runtime.h>
#include <math.h>

// DMLoss fused kernel for MI355X (gfx950).
// Round 7: R6's P=4 amortization spilled (122 MB scratch writes: full unroll +
// 64-VGPR cap). Same idea, spill-proof: P=2 owned points, 8-way scan split
// (16 segs/slice), packed seg constants (b128 + b64), #pragma unroll 2 to cap
// live ranges. LDS ops/thread 96 -> ~40 vs R3; VALU ~5.5us; target ~10us.
// Fused final reduction via atomic ticket (proven R4/R6).

#define BB 1024
#define NN 128
#define MM 128

__device__ __forceinline__ float sl1(float x) {
    float d = fabsf(x);
    return d < 1.0f ? 0.5f * d * d : d - 0.5f;
}

__global__ void __launch_bounds__(512, 8)
dmloss_main(const float* __restrict__ ini, const float* __restrict__ pred,
            const float* __restrict__ gt,  const float* __restrict__ kmask,
            float* __restrict__ pA, float* __restrict__ pB, float* __restrict__ pC,
            unsigned* __restrict__ counter, float* __restrict__ out)
{
    const int b   = blockIdx.x;
    const int tid = threadIdx.x;
    const int g   = tid & 63;    // owns points {2g, 2g+1}
    const int h   = tid >> 6;    // 0..7: scan slice (16 segments / 16 ini points)

    __shared__ __align__(16) float2 s_gt[MM];    // raw gt points
    __shared__ float2 s_pr[NN];                  // pred points (epilogue C gather)
    __shared__ float2 s_ii[NN];                  // ini points (Phase C scan)
    __shared__ float4 s_segA[MM];                // (ax, ay, Xn, Yn)
    __shared__ float2 s_segB[MM];                // (ex/10, ey/10)
    __shared__ float  s_step[16];                // exact j/10
    __shared__ float  s_rv[8 * 128];
    __shared__ float  s_rf[8 * 128];
    __shared__ float  s_sum[3][8];
    __shared__ int    s_last;

    const float2* gt2 = (const float2*)(gt   + (size_t)b * MM * 2);
    const float2* in2 = (const float2*)(ini  + (size_t)b * NN * 2);
    const float2* pr2 = (const float2*)(pred + (size_t)b * NN * 2);

    // ---- staging (one barrier) ----
    float2 myPr = make_float2(0.f, 0.f);
    float  myKm = 0.f;
    if (tid < 128) {
        int m = tid;
        float2 gm = gt2[m];
        float2 a  = gt2[(m + 127) & 127];
        s_gt[m] = gm;
        float ex = gm.x - a.x, ey = gm.y - a.y;
        float A  = ex * ex + ey * ey;
        float inv = A > 0.f ? 10.f / A : 0.f;   // degenerate seg -> vertex 0
        s_segA[m] = make_float4(a.x, a.y, -ex * inv, -ey * inv);
        s_segB[m] = make_float2(ex * 0.1f, ey * 0.1f);
        myPr = pr2[m];
        myKm = kmask[b * MM + m];
    } else if (tid < 256) {
        s_pr[tid - 128] = pr2[tid - 128];
    } else if (tid < 384) {
        s_ii[tid - 256] = in2[tid - 256];
    } else if (tid < 400) {
        s_step[tid - 384] = (float)(tid - 384) / 10.0f;
    }

    // Own pred (= ini_pred) points {2g, 2g+1}: one coalesced b128 global load.
    float4 pv = *(const float4*)(&in2[2 * g]);
    const float px0 = pv.x, py0 = pv.y, px1 = pv.z, py1 = pv.w;
    __syncthreads();

    float sumA = 0.f, sumB = 0.f, sumC = 0.f;

    // ---- Phase B: 2 owned pred points vs segment slice [16h, 16h+16) ----
    // Segment m: a=gt[m-1], e=gt[m]-a, q=a-p. jv = qx*Xn+qy*Yn (Xn=-ex*10/|e|^2).
    // Grid argmin at jr=rint(med3(jv,0,9)); d=|q+(e/10)*jr|^2; fi=10m+jr.
    float b0 = INFINITY, b1 = INFINITY;
    float f0 = 1e30f, f1 = 1e30f;
    {
        float fm = (float)(160 * h);     // 10 * 16h
        const int m0 = 16 * h;
        #pragma unroll 2
        for (int j = 0; j < 16; ++j) {
            float4 SA = s_segA[m0 + j];               // broadcast b128 (8 lanes/grp)
            float2 SB = s_segB[m0 + j];               // broadcast b64
            const float ax = SA.x, ay = SA.y, Xn = SA.z, Yn = SA.w;
            const float ux = SB.x, uy = SB.y;
            {
                float qx = ax - px0, qy = ay - py0;
                float jv = fmaf(qy, Yn, qx * Xn);
                float jr = rintf(__builtin_amdgcn_fmed3f(jv, 0.f, 9.f));
                float dx = fmaf(jr, ux, qx);
                float dy = fmaf(jr, uy, qy);
                float d  = fmaf(dy, dy, dx * dx);
                float fi = fm + jr;
                if (d < b0) { b0 = d; f0 = fi; }      // ascending -> first occ.
            }
            {
                float qx = ax - px1, qy = ay - py1;
                float jv = fmaf(qy, Yn, qx * Xn);
                float jr = rintf(__builtin_amdgcn_fmed3f(jv, 0.f, 9.f));
                float dx = fmaf(jr, ux, qx);
                float dy = fmaf(jr, uy, qy);
                float d  = fmaf(dy, dy, dx * dx);
                float fi = fm + jr;
                if (d < b1) { b1 = d; f1 = fi; }
            }
            fm += 10.f;
        }
    }
    {
        float2* rv2 = (float2*)&s_rv[h * 128 + 2 * g];
        float2* rf2 = (float2*)&s_rf[h * 128 + 2 * g];
        *rv2 = make_float2(b0, b1);
        *rf2 = make_float2(f0, f1);
    }
    __syncthreads();

    // merge 8 slices per point + exact epilogue A
    if (tid < 128) {
        float best = s_rv[tid], bf = s_rf[tid];
        #pragma unroll
        for (int q = 1; q < 8; ++q) {
            float ov = s_rv[q * 128 + tid];
            float of = s_rf[q * 128 + tid];
            if (ov < best || (ov == best && of < bf)) { best = ov; bf = of; }
        }
        int bidx = (int)bf;
        int m = bidx / 10;
        int j = bidx - m * 10;
        float s  = s_step[j];
        float tt = 1.0f - s;
        float2 gm = s_gt[m];
        float2 gp = s_gt[(m + 127) & 127];
        float gx = gm.x * s + gp.x * tt;   // exact reference interp formula
        float gy = gm.y * s + gp.y * tt;
        sumA = sl1(myPr.x - gx) + sl1(myPr.y - gy);
    }
    __syncthreads();   // protect s_rv/s_rf reuse

    // ---- Phase C: 2 owned gt points vs ini slice [16h, 16h+16) ----
    {
        float4 gv = *(const float4*)(&s_gt[2 * g]);
        const float gx0 = gv.x, gy0 = gv.y, gx1 = gv.z, gy1 = gv.w;
        b0 = INFINITY; b1 = INFINITY;
        f0 = 1e30f; f1 = 1e30f;
        float fk = (float)(16 * h);
        const int k0 = 16 * h;
        #pragma unroll 4
        for (int j = 0; j < 16; ++j) {
            float2 I = s_ii[k0 + j];                  // broadcast b64
            {
                float dx = I.x - gx0, dy = I.y - gy0;
                float d  = fmaf(dy, dy, dx * dx);
                if (d < b0) { b0 = d; f0 = fk; }
            }
            {
                float dx = I.x - gx1, dy = I.y - gy1;
                float d  = fmaf(dy, dy, dx * dx);
                if (d < b1) { b1 = d; f1 = fk; }
            }
            fk += 1.f;
        }
        float2* rv2 = (float2*)&s_rv[h * 128 + 2 * g];
        float2* rf2 = (float2*)&s_rf[h * 128 + 2 * g];
        *rv2 = make_float2(b0, b1);
        *rf2 = make_float2(f0, f1);
    }
    __syncthreads();

    if (tid < 128) {
        float best = s_rv[tid], bf = s_rf[tid];
        #pragma unroll
        for (int q = 1; q < 8; ++q) {
            float ov = s_rv[q * 128 + tid];
            float of = s_rf[q * 128 + tid];
            if (ov < best || (ov == best && of < bf)) { best = ov; bf = of; }
        }
        int k = (int)bf;
        float2 pk2 = s_pr[k];
        float2 g0  = s_gt[tid];
        sumB = myKm * (sl1(pk2.x - g0.x) + sl1(pk2.y - g0.y));
        sumC = myKm;
    }

    // ---- Block reduction of (sumA, sumB, sumC) ----
    #pragma unroll
    for (int off = 32; off > 0; off >>= 1) {
        sumA += __shfl_down(sumA, off);
        sumB += __shfl_down(sumB, off);
        sumC += __shfl_down(sumC, off);
    }
    const int wave = tid >> 6;
    if ((tid & 63) == 0) {
        s_sum[0][wave] = sumA; s_sum[1][wave] = sumB; s_sum[2][wave] = sumC;
    }
    __syncthreads();
    if (tid == 0) {
        float A = 0.f, Bs = 0.f, C = 0.f;
        #pragma unroll
        for (int w = 0; w < 8; ++w) {
            A += s_sum[0][w]; Bs += s_sum[1][w]; C += s_sum[2][w];
        }
        __hip_atomic_store(&pA[b], A,  __ATOMIC_RELAXED, __HIP_MEMORY_SCOPE_AGENT);
        __hip_atomic_store(&pB[b], Bs, __ATOMIC_RELAXED, __HIP_MEMORY_SCOPE_AGENT);
        __hip_atomic_store(&pC[b], C,  __ATOMIC_RELAXED, __HIP_MEMORY_SCOPE_AGENT);
        unsigned prev = __hip_atomic_fetch_add(counter, 1u, __ATOMIC_ACQ_REL,
                                               __HIP_MEMORY_SCOPE_AGENT);
        s_last = (prev == (unsigned)(BB - 1));
    }
    __syncthreads();

    // ---- Fused final reduction: exactly one block, fixed tid order ----
    if (s_last) {
        float A = 0.f, Bs = 0.f, C = 0.f;
        #pragma unroll
        for (int i = tid; i < BB; i += 512) {
            A  += __hip_atomic_load(&pA[i], __ATOMIC_RELAXED, __HIP_MEMORY_SCOPE_AGENT);
            Bs += __hip_atomic_load(&pB[i], __ATOMIC_RELAXED, __HIP_MEMORY_SCOPE_AGENT);
            C  += __hip_atomic_load(&pC[i], __ATOMIC_RELAXED, __HIP_MEMORY_SCOPE_AGENT);
        }
        #pragma unroll
        for (int off = 32; off > 0; off >>= 1) {
            A  += __shfl_down(A, off);
            Bs += __shfl_down(Bs, off);
            C  += __shfl_down(C, off);
        }
        if ((tid & 63) == 0) {
            s_sum[0][wave] = A; s_sum[1][wave] = Bs; s_sum[2][wave] = C;
        }
        __syncthreads();
        if (tid == 0) {
            float a = 0.f, bs = 0.f, c = 0.f;
            #pragma unroll
            for (int w = 0; w < 8; ++w) {
                a += s_sum[0][w]; bs += s_sum[1][w]; c += s_sum[2][w];
            }
            float loss_pred2gt = a / ((float)BB * (float)NN * 2.0f);
            float loss_set2set = bs / (2.0f * c + 1.0f) + loss_pred2gt;
            out[0] = 0.5f * loss_set2set;
        }
    }
}

extern "C" void kernel_launch(void* const* d_in, const int* in_sizes, int n_in,
                              void* d_out, int out_size, void* d_ws, size_t ws_size,
                              hipStream_t stream)
{
    const float* ini   = (const float*)d_in[0];
    const float* pred  = (const float*)d_in[1];
    const float* gt    = (const float*)d_in[2];
    const float* kmask = (const float*)d_in[3];

    float*    pA      = (float*)d_ws;             // [1024]
    float*    pB      = pA + BB;                  // [1024]
    float*    pC      = pB + BB;                  // [1024]
    unsigned* counter = (unsigned*)(pC + BB);     // [1]

    hipMemsetAsync(counter, 0, sizeof(unsigned), stream);
    dmloss_main<<<dim3(BB), dim3(512), 0, stream>>>(ini, pred, gt, kmask,
                                                    pA, pB, pC, counter,
                                                    (float*)d_out);
}

// Round 8
// 33.645 us; speedup vs baseline: 2.2638x; 1.0030x over previous
//
#include <hip/hip_runtime.h>
#include <math.h>

// DMLoss fused kernel for MI355X (gfx950).
// Round 8: single-variable change vs R7 -> __launch_bounds__(512, 4).
// R6/R7's regressions are attributed to the 64-VGPR cap from (512,8) forcing
// spills in the P-amortized loops (R6: 122 MB scratch writes at VGPR=32).
// With a 128-VGPR cap the kernel's natural ~56 VGPRs fit spill-free; if the
// compiler lands <=64 we still get 32 waves/CU. Everything else identical to
// R7 (P=2 owned points, 8-way scan split, packed seg constants, fused ticket).

#define BB 1024
#define NN 128
#define MM 128

__device__ __forceinline__ float sl1(float x) {
    float d = fabsf(x);
    return d < 1.0f ? 0.5f * d * d : d - 0.5f;
}

__global__ void __launch_bounds__(512, 4)
dmloss_main(const float* __restrict__ ini, const float* __restrict__ pred,
            const float* __restrict__ gt,  const float* __restrict__ kmask,
            float* __restrict__ pA, float* __restrict__ pB, float* __restrict__ pC,
            unsigned* __restrict__ counter, float* __restrict__ out)
{
    const int b   = blockIdx.x;
    const int tid = threadIdx.x;
    const int g   = tid & 63;    // owns points {2g, 2g+1}
    const int h   = tid >> 6;    // 0..7: scan slice (16 segments / 16 ini points)

    __shared__ __align__(16) float2 s_gt[MM];    // raw gt points
    __shared__ float2 s_pr[NN];                  // pred points (epilogue C gather)
    __shared__ float2 s_ii[NN];                  // ini points (Phase C scan)
    __shared__ float4 s_segA[MM];                // (ax, ay, Xn, Yn)
    __shared__ float2 s_segB[MM];                // (ex/10, ey/10)
    __shared__ float  s_step[16];                // exact j/10
    __shared__ float  s_rv[8 * 128];
    __shared__ float  s_rf[8 * 128];
    __shared__ float  s_sum[3][8];
    __shared__ int    s_last;

    const float2* gt2 = (const float2*)(gt   + (size_t)b * MM * 2);
    const float2* in2 = (const float2*)(ini  + (size_t)b * NN * 2);
    const float2* pr2 = (const float2*)(pred + (size_t)b * NN * 2);

    // ---- staging (one barrier) ----
    float2 myPr = make_float2(0.f, 0.f);
    float  myKm = 0.f;
    if (tid < 128) {
        int m = tid;
        float2 gm = gt2[m];
        float2 a  = gt2[(m + 127) & 127];
        s_gt[m] = gm;
        float ex = gm.x - a.x, ey = gm.y - a.y;
        float A  = ex * ex + ey * ey;
        float inv = A > 0.f ? 10.f / A : 0.f;   // degenerate seg -> vertex 0
        s_segA[m] = make_float4(a.x, a.y, -ex * inv, -ey * inv);
        s_segB[m] = make_float2(ex * 0.1f, ey * 0.1f);
        myPr = pr2[m];
        myKm = kmask[b * MM + m];
    } else if (tid < 256) {
        s_pr[tid - 128] = pr2[tid - 128];
    } else if (tid < 384) {
        s_ii[tid - 256] = in2[tid - 256];
    } else if (tid < 400) {
        s_step[tid - 384] = (float)(tid - 384) / 10.0f;
    }

    // Own pred (= ini_pred) points {2g, 2g+1}: one coalesced b128 global load.
    float4 pv = *(const float4*)(&in2[2 * g]);
    const float px0 = pv.x, py0 = pv.y, px1 = pv.z, py1 = pv.w;
    __syncthreads();

    float sumA = 0.f, sumB = 0.f, sumC = 0.f;

    // ---- Phase B: 2 owned pred points vs segment slice [16h, 16h+16) ----
    // Segment m: a=gt[m-1], e=gt[m]-a, q=a-p. jv = qx*Xn+qy*Yn (Xn=-ex*10/|e|^2).
    // Grid argmin at jr=rint(med3(jv,0,9)); d=|q+(e/10)*jr|^2; fi=10m+jr.
    float b0 = INFINITY, b1 = INFINITY;
    float f0 = 1e30f, f1 = 1e30f;
    {
        float fm = (float)(160 * h);     // 10 * 16h
        const int m0 = 16 * h;
        #pragma unroll 2
        for (int j = 0; j < 16; ++j) {
            float4 SA = s_segA[m0 + j];               // broadcast b128 (wave-uniform)
            float2 SB = s_segB[m0 + j];               // broadcast b64
            const float ax = SA.x, ay = SA.y, Xn = SA.z, Yn = SA.w;
            const float ux = SB.x, uy = SB.y;
            {
                float qx = ax - px0, qy = ay - py0;
                float jv = fmaf(qy, Yn, qx * Xn);
                float jr = rintf(__builtin_amdgcn_fmed3f(jv, 0.f, 9.f));
                float dx = fmaf(jr, ux, qx);
                float dy = fmaf(jr, uy, qy);
                float d  = fmaf(dy, dy, dx * dx);
                float fi = fm + jr;
                if (d < b0) { b0 = d; f0 = fi; }      // ascending -> first occ.
            }
            {
                float qx = ax - px1, qy = ay - py1;
                float jv = fmaf(qy, Yn, qx * Xn);
                float jr = rintf(__builtin_amdgcn_fmed3f(jv, 0.f, 9.f));
                float dx = fmaf(jr, ux, qx);
                float dy = fmaf(jr, uy, qy);
                float d  = fmaf(dy, dy, dx * dx);
                float fi = fm + jr;
                if (d < b1) { b1 = d; f1 = fi; }
            }
            fm += 10.f;
        }
    }
    {
        float2* rv2 = (float2*)&s_rv[h * 128 + 2 * g];
        float2* rf2 = (float2*)&s_rf[h * 128 + 2 * g];
        *rv2 = make_float2(b0, b1);
        *rf2 = make_float2(f0, f1);
    }
    __syncthreads();

    // merge 8 slices per point + exact epilogue A
    if (tid < 128) {
        float best = s_rv[tid], bf = s_rf[tid];
        #pragma unroll
        for (int q = 1; q < 8; ++q) {
            float ov = s_rv[q * 128 + tid];
            float of = s_rf[q * 128 + tid];
            if (ov < best || (ov == best && of < bf)) { best = ov; bf = of; }
        }
        int bidx = (int)bf;
        int m = bidx / 10;
        int j = bidx - m * 10;
        float s  = s_step[j];
        float tt = 1.0f - s;
        float2 gm = s_gt[m];
        float2 gp = s_gt[(m + 127) & 127];
        float gx = gm.x * s + gp.x * tt;   // exact reference interp formula
        float gy = gm.y * s + gp.y * tt;
        sumA = sl1(myPr.x - gx) + sl1(myPr.y - gy);
    }
    __syncthreads();   // protect s_rv/s_rf reuse

    // ---- Phase C: 2 owned gt points vs ini slice [16h, 16h+16) ----
    {
        float4 gv = *(const float4*)(&s_gt[2 * g]);
        const float gx0 = gv.x, gy0 = gv.y, gx1 = gv.z, gy1 = gv.w;
        b0 = INFINITY; b1 = INFINITY;
        f0 = 1e30f; f1 = 1e30f;
        float fk = (float)(16 * h);
        const int k0 = 16 * h;
        #pragma unroll 4
        for (int j = 0; j < 16; ++j) {
            float2 I = s_ii[k0 + j];                  // broadcast b64
            {
                float dx = I.x - gx0, dy = I.y - gy0;
                float d  = fmaf(dy, dy, dx * dx);
                if (d < b0) { b0 = d; f0 = fk; }
            }
            {
                float dx = I.x - gx1, dy = I.y - gy1;
                float d  = fmaf(dy, dy, dx * dx);
                if (d < b1) { b1 = d; f1 = fk; }
            }
            fk += 1.f;
        }
        float2* rv2 = (float2*)&s_rv[h * 128 + 2 * g];
        float2* rf2 = (float2*)&s_rf[h * 128 + 2 * g];
        *rv2 = make_float2(b0, b1);
        *rf2 = make_float2(f0, f1);
    }
    __syncthreads();

    if (tid < 128) {
        float best = s_rv[tid], bf = s_rf[tid];
        #pragma unroll
        for (int q = 1; q < 8; ++q) {
            float ov = s_rv[q * 128 + tid];
            float of = s_rf[q * 128 + tid];
            if (ov < best || (ov == best && of < bf)) { best = ov; bf = of; }
        }
        int k = (int)bf;
        float2 pk2 = s_pr[k];
        float2 g0  = s_gt[tid];
        sumB = myKm * (sl1(pk2.x - g0.x) + sl1(pk2.y - g0.y));
        sumC = myKm;
    }

    // ---- Block reduction of (sumA, sumB, sumC) ----
    #pragma unroll
    for (int off = 32; off > 0; off >>= 1) {
        sumA += __shfl_down(sumA, off);
        sumB += __shfl_down(sumB, off);
        sumC += __shfl_down(sumC, off);
    }
    const int wave = tid >> 6;
    if ((tid & 63) == 0) {
        s_sum[0][wave] = sumA; s_sum[1][wave] = sumB; s_sum[2][wave] = sumC;
    }
    __syncthreads();
    if (tid == 0) {
        float A = 0.f, Bs = 0.f, C = 0.f;
        #pragma unroll
        for (int w = 0; w < 8; ++w) {
            A += s_sum[0][w]; Bs += s_sum[1][w]; C += s_sum[2][w];
        }
        __hip_atomic_store(&pA[b], A,  __ATOMIC_RELAXED, __HIP_MEMORY_SCOPE_AGENT);
        __hip_atomic_store(&pB[b], Bs, __ATOMIC_RELAXED, __HIP_MEMORY_SCOPE_AGENT);
        __hip_atomic_store(&pC[b], C,  __ATOMIC_RELAXED, __HIP_MEMORY_SCOPE_AGENT);
        unsigned prev = __hip_atomic_fetch_add(counter, 1u, __ATOMIC_ACQ_REL,
                                               __HIP_MEMORY_SCOPE_AGENT);
        s_last = (prev == (unsigned)(BB - 1));
    }
    __syncthreads();

    // ---- Fused final reduction: exactly one block, fixed tid order ----
    if (s_last) {
        float A = 0.f, Bs = 0.f, C = 0.f;
        #pragma unroll
        for (int i = tid; i < BB; i += 512) {
            A  += __hip_atomic_load(&pA[i], __ATOMIC_RELAXED, __HIP_MEMORY_SCOPE_AGENT);
            Bs += __hip_atomic_load(&pB[i], __ATOMIC_RELAXED, __HIP_MEMORY_SCOPE_AGENT);
            C  += __hip_atomic_load(&pC[i], __ATOMIC_RELAXED, __HIP_MEMORY_SCOPE_AGENT);
        }
        #pragma unroll
        for (int off = 32; off > 0; off >>= 1) {
            A  += __shfl_down(A, off);
            Bs += __shfl_down(Bs, off);
            C  += __shfl_down(C, off);
        }
        if ((tid & 63) == 0) {
            s_sum[0][wave] = A; s_sum[1][wave] = Bs; s_sum[2][wave] = C;
        }
        __syncthreads();
        if (tid == 0) {
            float a = 0.f, bs = 0.f, c = 0.f;
            #pragma unroll
            for (int w = 0; w < 8; ++w) {
                a += s_sum[0][w]; bs += s_sum[1][w]; c += s_sum[2][w];
            }
            float loss_pred2gt = a / ((float)BB * (float)NN * 2.0f);
            float loss_set2set = bs / (2.0f * c + 1.0f) + loss_pred2gt;
            out[0] = 0.5f * loss_set2set;
        }
    }
}

extern "C" void kernel_launch(void* const* d_in, const int* in_sizes, int n_in,
                              void* d_out, int out_size, void* d_ws, size_t ws_size,
                              hipStream_t stream)
{
    const float* ini   = (const float*)d_in[0];
    const float* pred  = (const float*)d_in[1];
    const float* gt    = (const float*)d_in[2];
    const float* kmask = (const float*)d_in[3];

    float*    pA      = (float*)d_ws;             // [1024]
    float*    pB      = pA + BB;                  // [1024]
    float*    pC      = pB + BB;                  // [1024]
    unsigned* counter = (unsigned*)(pC + BB);     // [1]

    hipMemsetAsync(counter, 0, sizeof(unsigned), stream);
    dmloss_main<<<dim3(BB), dim3(512), 0, stream>>>(ini, pred, gt, kmask,
                                                    pA, pB, pC, counter,
                                                    (float*)d_out);
}

// Round 9
// 19.080 us; speedup vs baseline: 3.9920x; 1.7634x over previous
//
#include <hip/hip_runtime.h>
#include <math.h>

// DMLoss fused kernel for MI355X (gfx950).
// Round 9: bisection. Every atomic-ticket round (R4-R8) was >=32us while the
// two-kernel rounds (R2/R3) were 19-29us: agent-scope ACQ_REL fetch_add per
// block forces cache-invalidates on non-coherent per-XCD L2s (+ serialized
// same-address RMW + extra memset dispatch). Drop the ticket, keep R7's P=2
// amortized scan loops (LDS ops/thread 96 -> ~48 vs R3), two-kernel structure.

#define BB 1024
#define NN 128
#define MM 128

__device__ __forceinline__ float sl1(float x) {
    float d = fabsf(x);
    return d < 1.0f ? 0.5f * d * d : d - 0.5f;
}

__global__ void __launch_bounds__(512, 4)
dmloss_main(const float* __restrict__ ini, const float* __restrict__ pred,
            const float* __restrict__ gt,  const float* __restrict__ kmask,
            float4* __restrict__ partials)
{
    const int b   = blockIdx.x;
    const int tid = threadIdx.x;
    const int g   = tid & 63;    // owns points {2g, 2g+1}
    const int h   = tid >> 6;    // 0..7: scan slice (16 segments / 16 ini points)

    __shared__ __align__(16) float2 s_gt[MM];    // raw gt points
    __shared__ float2 s_pr[NN];                  // pred points (epilogue C gather)
    __shared__ float2 s_ii[NN];                  // ini points (Phase C scan)
    __shared__ float4 s_segA[MM];                // (ax, ay, Xn, Yn)
    __shared__ float2 s_segB[MM];                // (ex/10, ey/10)
    __shared__ float  s_step[16];                // exact j/10
    __shared__ float  s_rv[8 * 128];
    __shared__ float  s_rf[8 * 128];
    __shared__ float  s_sum[3][8];

    const float2* gt2 = (const float2*)(gt   + (size_t)b * MM * 2);
    const float2* in2 = (const float2*)(ini  + (size_t)b * NN * 2);
    const float2* pr2 = (const float2*)(pred + (size_t)b * NN * 2);

    // ---- staging (one barrier) ----
    float2 myPr = make_float2(0.f, 0.f);
    float  myKm = 0.f;
    if (tid < 128) {
        int m = tid;
        float2 gm = gt2[m];
        float2 a  = gt2[(m + 127) & 127];
        s_gt[m] = gm;
        float ex = gm.x - a.x, ey = gm.y - a.y;
        float A  = ex * ex + ey * ey;
        float inv = A > 0.f ? 10.f / A : 0.f;   // degenerate seg -> vertex 0
        s_segA[m] = make_float4(a.x, a.y, -ex * inv, -ey * inv);
        s_segB[m] = make_float2(ex * 0.1f, ey * 0.1f);
        myPr = pr2[m];
        myKm = kmask[b * MM + m];
    } else if (tid < 256) {
        s_pr[tid - 128] = pr2[tid - 128];
    } else if (tid < 384) {
        s_ii[tid - 256] = in2[tid - 256];
    } else if (tid < 400) {
        s_step[tid - 384] = (float)(tid - 384) / 10.0f;
    }

    // Own pred (= ini_pred) points {2g, 2g+1}: one coalesced b128 global load.
    float4 pv = *(const float4*)(&in2[2 * g]);
    const float px0 = pv.x, py0 = pv.y, px1 = pv.z, py1 = pv.w;
    __syncthreads();

    float sumA = 0.f, sumB = 0.f, sumC = 0.f;

    // ---- Phase B: 2 owned pred points vs segment slice [16h, 16h+16) ----
    // Segment m: a=gt[m-1], e=gt[m]-a, q=a-p. jv = qx*Xn+qy*Yn (Xn=-ex*10/|e|^2).
    // Grid argmin at jr=rint(med3(jv,0,9)); d=|q+(e/10)*jr|^2; fi=10m+jr.
    float b0 = INFINITY, b1 = INFINITY;
    float f0 = 1e30f, f1 = 1e30f;
    {
        float fm = (float)(160 * h);     // 10 * 16h
        const int m0 = 16 * h;
        #pragma unroll 2
        for (int j = 0; j < 16; ++j) {
            float4 SA = s_segA[m0 + j];               // broadcast b128 (wave-uniform)
            float2 SB = s_segB[m0 + j];               // broadcast b64
            const float ax = SA.x, ay = SA.y, Xn = SA.z, Yn = SA.w;
            const float ux = SB.x, uy = SB.y;
            {
                float qx = ax - px0, qy = ay - py0;
                float jv = fmaf(qy, Yn, qx * Xn);
                float jr = rintf(__builtin_amdgcn_fmed3f(jv, 0.f, 9.f));
                float dx = fmaf(jr, ux, qx);
                float dy = fmaf(jr, uy, qy);
                float d  = fmaf(dy, dy, dx * dx);
                float fi = fm + jr;
                if (d < b0) { b0 = d; f0 = fi; }      // ascending -> first occ.
            }
            {
                float qx = ax - px1, qy = ay - py1;
                float jv = fmaf(qy, Yn, qx * Xn);
                float jr = rintf(__builtin_amdgcn_fmed3f(jv, 0.f, 9.f));
                float dx = fmaf(jr, ux, qx);
                float dy = fmaf(jr, uy, qy);
                float d  = fmaf(dy, dy, dx * dx);
                float fi = fm + jr;
                if (d < b1) { b1 = d; f1 = fi; }
            }
            fm += 10.f;
        }
    }
    {
        float2* rv2 = (float2*)&s_rv[h * 128 + 2 * g];
        float2* rf2 = (float2*)&s_rf[h * 128 + 2 * g];
        *rv2 = make_float2(b0, b1);
        *rf2 = make_float2(f0, f1);
    }
    __syncthreads();

    // merge 8 slices per point + exact epilogue A
    if (tid < 128) {
        float best = s_rv[tid], bf = s_rf[tid];
        #pragma unroll
        for (int q = 1; q < 8; ++q) {
            float ov = s_rv[q * 128 + tid];
            float of = s_rf[q * 128 + tid];
            if (ov < best || (ov == best && of < bf)) { best = ov; bf = of; }
        }
        int bidx = (int)bf;
        int m = bidx / 10;
        int j = bidx - m * 10;
        float s  = s_step[j];
        float tt = 1.0f - s;
        float2 gm = s_gt[m];
        float2 gp = s_gt[(m + 127) & 127];
        float gx = gm.x * s + gp.x * tt;   // exact reference interp formula
        float gy = gm.y * s + gp.y * tt;
        sumA = sl1(myPr.x - gx) + sl1(myPr.y - gy);
    }
    __syncthreads();   // protect s_rv/s_rf reuse

    // ---- Phase C: 2 owned gt points vs ini slice [16h, 16h+16) ----
    {
        float4 gv = *(const float4*)(&s_gt[2 * g]);
        const float gx0 = gv.x, gy0 = gv.y, gx1 = gv.z, gy1 = gv.w;
        b0 = INFINITY; b1 = INFINITY;
        f0 = 1e30f; f1 = 1e30f;
        float fk = (float)(16 * h);
        const int k0 = 16 * h;
        #pragma unroll 4
        for (int j = 0; j < 16; ++j) {
            float2 I = s_ii[k0 + j];                  // broadcast b64
            {
                float dx = I.x - gx0, dy = I.y - gy0;
                float d  = fmaf(dy, dy, dx * dx);
                if (d < b0) { b0 = d; f0 = fk; }
            }
            {
                float dx = I.x - gx1, dy = I.y - gy1;
                float d  = fmaf(dy, dy, dx * dx);
                if (d < b1) { b1 = d; f1 = fk; }
            }
            fk += 1.f;
        }
        float2* rv2 = (float2*)&s_rv[h * 128 + 2 * g];
        float2* rf2 = (float2*)&s_rf[h * 128 + 2 * g];
        *rv2 = make_float2(b0, b1);
        *rf2 = make_float2(f0, f1);
    }
    __syncthreads();

    if (tid < 128) {
        float best = s_rv[tid], bf = s_rf[tid];
        #pragma unroll
        for (int q = 1; q < 8; ++q) {
            float ov = s_rv[q * 128 + tid];
            float of = s_rf[q * 128 + tid];
            if (ov < best || (ov == best && of < bf)) { best = ov; bf = of; }
        }
        int k = (int)bf;
        float2 pk2 = s_pr[k];
        float2 g0  = s_gt[tid];
        sumB = myKm * (sl1(pk2.x - g0.x) + sl1(pk2.y - g0.y));
        sumC = myKm;
    }

    // ---- Block reduction of (sumA, sumB, sumC) ----
    #pragma unroll
    for (int off = 32; off > 0; off >>= 1) {
        sumA += __shfl_down(sumA, off);
        sumB += __shfl_down(sumB, off);
        sumC += __shfl_down(sumC, off);
    }
    const int wave = tid >> 6;
    if ((tid & 63) == 0) {
        s_sum[0][wave] = sumA; s_sum[1][wave] = sumB; s_sum[2][wave] = sumC;
    }
    __syncthreads();
    if (tid == 0) {
        float A = 0.f, Bs = 0.f, C = 0.f;
        #pragma unroll
        for (int w = 0; w < 8; ++w) {
            A += s_sum[0][w]; Bs += s_sum[1][w]; C += s_sum[2][w];
        }
        partials[b] = make_float4(A, Bs, C, 0.0f);
    }
}

__global__ void __launch_bounds__(256)
dmloss_final(const float4* __restrict__ partials, float* __restrict__ out)
{
    const int tid = threadIdx.x;
    float A = 0.0f, Bs = 0.0f, C = 0.0f;
    #pragma unroll
    for (int i = tid; i < BB; i += 256) {
        float4 p = partials[i];
        A += p.x; Bs += p.y; C += p.z;
    }
    #pragma unroll
    for (int off = 32; off > 0; off >>= 1) {
        A  += __shfl_down(A, off);
        Bs += __shfl_down(Bs, off);
        C  += __shfl_down(C, off);
    }
    __shared__ float sA[4], sB[4], sC[4];
    const int wave = tid >> 6, lane = tid & 63;
    if (lane == 0) { sA[wave] = A; sB[wave] = Bs; sC[wave] = C; }
    __syncthreads();
    if (tid == 0) {
        float a  = sA[0] + sA[1] + sA[2] + sA[3];
        float bs = sB[0] + sB[1] + sB[2] + sB[3];
        float c  = sC[0] + sC[1] + sC[2] + sC[3];
        float loss_pred2gt = a / ((float)BB * (float)NN * 2.0f);
        float loss_set2set = bs / (2.0f * c + 1.0f) + loss_pred2gt;
        out[0] = 0.5f * loss_set2set;
    }
}

extern "C" void kernel_launch(void* const* d_in, const int* in_sizes, int n_in,
                              void* d_out, int out_size, void* d_ws, size_t ws_size,
                              hipStream_t stream)
{
    const float* ini   = (const float*)d_in[0];
    const float* pred  = (const float*)d_in[1];
    const float* gt    = (const float*)d_in[2];
    const float* kmask = (const float*)d_in[3];
    float4* partials = (float4*)d_ws;   // 1024 * 16 B = 16 KiB

    dmloss_main<<<dim3(BB), dim3(512), 0, stream>>>(ini, pred, gt, kmask, partials);
    dmloss_final<<<dim3(1), dim3(256), 0, stream>>>(partials, (float*)d_out);
}